// Round 12
// baseline (318.286 us; speedup 1.0000x reference)
//
#include <hip/hip_runtime.h>
#include <hip/hip_bf16.h>

// RelAttention (Transformer-XL style) on MI355X.
// fp32 in/out; internal bf16 MFMA w/ fp32 accum.
// B=4, S=1024, D=1024, H=16, DH=64, BH=64. SCALE = 1/32.
//
// Pipeline: cvt -> fused QKV GEMM (m97-style) -> fused rel-attention
// (64-row tiles, 1024 threads = 4 waves/SIMD, fixed-shift softmax fused
// into AC pass, deferred normalization) -> final GEMM (128x64 tiles).

typedef __bf16 bf16x8 __attribute__((ext_vector_type(8)));
typedef float  f32x4  __attribute__((ext_vector_type(4)));
typedef unsigned short u16x4 __attribute__((ext_vector_type(4)));

struct alignas(16) U128 { unsigned long long lo, hi; };

__device__ __forceinline__ bf16x8 ldg8(const __hip_bfloat16* p) {
    U128 u = *reinterpret_cast<const U128*>(p);
    return __builtin_bit_cast(bf16x8, u);
}

__device__ __forceinline__ __bf16 f2b(float f) {
    __hip_bfloat16 h = __float2bfloat16(f);
    return __builtin_bit_cast(__bf16, h);
}
__device__ __forceinline__ unsigned short f2bu(float f) {
    __hip_bfloat16 h = __float2bfloat16(f);
    return __builtin_bit_cast(unsigned short, h);
}
__device__ __forceinline__ float b2f(__bf16 b) {
    __hip_bfloat16 h = __builtin_bit_cast(__hip_bfloat16, b);
    return __bfloat162float(h);
}

__device__ __forceinline__ bf16x8 ldg8cvt(const float* p) {
    f32x4 a = *reinterpret_cast<const f32x4*>(p);
    f32x4 b = *reinterpret_cast<const f32x4*>(p + 4);
    bf16x8 r;
    r[0] = f2b(a[0]); r[1] = f2b(a[1]); r[2] = f2b(a[2]); r[3] = f2b(a[3]);
    r[4] = f2b(b[0]); r[5] = f2b(b[1]); r[6] = f2b(b[2]); r[7] = f2b(b[3]);
    return r;
}

#define MFMA16(a, b, c) __builtin_amdgcn_mfma_f32_16x16x32_bf16((a), (b), (c), 0, 0, 0)

__device__ __forceinline__ void gll16(const __hip_bfloat16* g, void* lds_wave_base) {
    __builtin_amdgcn_global_load_lds(
        (const __attribute__((address_space(1))) void*)g,
        (__attribute__((address_space(3))) void*)lds_wave_base,
        16, 0, 0);
}

// ---------------------------------------------------------------------------
// fp32 -> bf16: x(4M), pos(4M), Wq/Wk/Wv(3M stacked), Wc(1M) = 12M elems.
// ---------------------------------------------------------------------------
__global__ __launch_bounds__(256) void cvt_kernel(
    const float* __restrict__ x,  const float* __restrict__ pos,
    const float* __restrict__ wq, const float* __restrict__ wk,
    const float* __restrict__ wv, const float* __restrict__ wc,
    __hip_bfloat16* __restrict__ xb, __hip_bfloat16* __restrict__ posb,
    __hip_bfloat16* __restrict__ wqkvb, __hip_bfloat16* __restrict__ wcb)
{
    const size_t base = ((size_t)blockIdx.x * 256 + threadIdx.x) * 8;
    const size_t M1 = (size_t)1 << 20;
    const float* src; __hip_bfloat16* dst; size_t o;
    if (base < 4*M1)        { src = x;   dst = xb;           o = base; }
    else if (base < 8*M1)   { src = pos; dst = posb;         o = base - 4*M1; }
    else if (base < 9*M1)   { src = wq;  dst = wqkvb;        o = base - 8*M1; }
    else if (base < 10*M1)  { src = wk;  dst = wqkvb + M1;   o = base - 9*M1; }
    else if (base < 11*M1)  { src = wv;  dst = wqkvb + 2*M1; o = base - 10*M1; }
    else                    { src = wc;  dst = wcb;          o = base - 11*M1; }
    *(bf16x8*)(dst + o) = ldg8cvt(src + o);
}

// ---------------------------------------------------------------------------
// QKV GEMM (m97-style): C[m][n] = sum_k A[m][k]*Bm[n][k], Bm=[3072][1024].
// n<1024 -> Qu = C+bq+u; <2048 -> Kb = C+bk; else Vt head-transposed = C+bv.
// ---------------------------------------------------------------------------
__global__ __launch_bounds__(256) void gemm_qkv(
    const __hip_bfloat16* __restrict__ A,
    const __hip_bfloat16* __restrict__ Bm,
    const float* __restrict__ bq, const float* __restrict__ bk,
    const float* __restrict__ bv, const float* __restrict__ u,
    __hip_bfloat16* __restrict__ Qu,
    __hip_bfloat16* __restrict__ Kb, __hip_bfloat16* __restrict__ Vt)
{
    __shared__ __hip_bfloat16 As[128 * 32];
    __shared__ __hip_bfloat16 Bs[128 * 32];

    const int tid  = threadIdx.x;
    const int lane = tid & 63, w = tid >> 6;
    const int quad = lane >> 4, c16 = lane & 15;
    const int wm = w >> 1, wn = w & 1;
    const int m0 = blockIdx.y * 128;
    const int n0 = blockIdx.x * 128;

    const int srow = w * 16 + (lane >> 2);
    const int scol = (lane & 3) * 8;
    const __hip_bfloat16* gA0 = A  + (size_t)(m0 + srow) * 1024 + scol;
    const __hip_bfloat16* gA1 = gA0 + (size_t)64 * 1024;
    const __hip_bfloat16* gB0 = Bm + (size_t)(n0 + srow) * 1024 + scol;
    const __hip_bfloat16* gB1 = gB0 + (size_t)64 * 1024;
    char* ldsA0 = (char*)As + (w << 10);
    char* ldsA1 = ldsA0 + 4096;
    char* ldsB0 = (char*)Bs + (w << 10);
    char* ldsB1 = ldsB0 + 4096;

    f32x4 acc[4][4] = {};

    for (int k0 = 0; k0 < 1024; k0 += 32) {
        gll16(gA0 + k0, ldsA0);
        gll16(gA1 + k0, ldsA1);
        gll16(gB0 + k0, ldsB0);
        gll16(gB1 + k0, ldsB1);
        __syncthreads();

        bf16x8 af[4], bfr[4];
        #pragma unroll
        for (int i = 0; i < 4; ++i) {
            af[i]  = *(const bf16x8*)&As[(wm * 64 + i * 16 + c16) * 32 + quad * 8];
            bfr[i] = *(const bf16x8*)&Bs[(wn * 64 + i * 16 + c16) * 32 + quad * 8];
        }
        #pragma unroll
        for (int mi = 0; mi < 4; ++mi)
            #pragma unroll
            for (int ni = 0; ni < 4; ++ni)
                acc[mi][ni] = MFMA16(af[mi], bfr[ni], acc[mi][ni]);
        __syncthreads();
    }

    #pragma unroll
    for (int mi = 0; mi < 4; ++mi) {
        #pragma unroll
        for (int ni = 0; ni < 4; ++ni) {
            const int m = m0 + wm * 64 + mi * 16 + quad * 4;  // +r
            const int n = n0 + wn * 64 + ni * 16 + c16;
            if (n < 1024) {
                const float b0 = bq[n] + u[n & 63];
                #pragma unroll
                for (int r = 0; r < 4; ++r)
                    Qu[(size_t)(m + r) * 1024 + n] =
                        __float2bfloat16(acc[mi][ni][r] + b0);
            } else if (n < 2048) {
                const int nn = n - 1024;
                const float b0 = bk[nn];
                #pragma unroll
                for (int r = 0; r < 4; ++r)
                    Kb[(size_t)(m + r) * 1024 + nn] =
                        __float2bfloat16(acc[mi][ni][r] + b0);
            } else {
                const int nn = n - 2048;
                const float b0 = bv[nn];
                const int d = nn & 63, hh = nn >> 6;
                const int bb = m >> 10, s = m & 1023;
                u16x4 pk;
                #pragma unroll
                for (int r = 0; r < 4; ++r)
                    pk[r] = f2bu(acc[mi][ni][r] + b0);
                *(u16x4*)&Vt[(((size_t)(bb * 16 + hh) * 64 + d) << 10) + s] = pk;
            }
        }
    }
}

// ---------------------------------------------------------------------------
// Final GEMM, 128x64 tiles (grid 16x32 = 512 blocks -> 2 blocks/CU).
// Wave (2x2): 64x32 sub-tile, acc[4][2] -> 8 MFMA / 6 fragment loads.
// ---------------------------------------------------------------------------
__global__ __launch_bounds__(256) void gemm_fin(
    const __hip_bfloat16* __restrict__ A,
    const __hip_bfloat16* __restrict__ Bm,
    float* __restrict__ dout, const float* __restrict__ bc)
{
    __shared__ __hip_bfloat16 As[128 * 32];   // 8 KiB
    __shared__ __hip_bfloat16 Bs[64 * 32];    // 4 KiB

    const int tid  = threadIdx.x;
    const int lane = tid & 63, w = tid >> 6;
    const int quad = lane >> 4, c16 = lane & 15;
    const int wm = w >> 1, wn = w & 1;
    const int m0 = blockIdx.y * 128;
    const int n0 = blockIdx.x * 64;

    const int srow = w * 16 + (lane >> 2);
    const int scol = (lane & 3) * 8;
    const __hip_bfloat16* gA0 = A  + (size_t)(m0 + srow) * 1024 + scol;
    const __hip_bfloat16* gA1 = gA0 + (size_t)64 * 1024;
    const __hip_bfloat16* gB0 = Bm + (size_t)(n0 + srow) * 1024 + scol;
    char* ldsA0 = (char*)As + (w << 10);
    char* ldsA1 = ldsA0 + 4096;
    char* ldsB0 = (char*)Bs + (w << 10);

    f32x4 acc[4][2] = {};

    for (int k0 = 0; k0 < 1024; k0 += 32) {
        gll16(gA0 + k0, ldsA0);
        gll16(gA1 + k0, ldsA1);
        gll16(gB0 + k0, ldsB0);
        __syncthreads();

        bf16x8 af[4], bfr[2];
        #pragma unroll
        for (int i = 0; i < 4; ++i)
            af[i] = *(const bf16x8*)&As[(wm * 64 + i * 16 + c16) * 32 + quad * 8];
        #pragma unroll
        for (int i = 0; i < 2; ++i)
            bfr[i] = *(const bf16x8*)&Bs[(wn * 32 + i * 16 + c16) * 32 + quad * 8];
        #pragma unroll
        for (int mi = 0; mi < 4; ++mi)
            #pragma unroll
            for (int ni = 0; ni < 2; ++ni)
                acc[mi][ni] = MFMA16(af[mi], bfr[ni], acc[mi][ni]);
        __syncthreads();
    }

    #pragma unroll
    for (int mi = 0; mi < 4; ++mi) {
        #pragma unroll
        for (int ni = 0; ni < 2; ++ni) {
            const int m = m0 + wm * 64 + mi * 16 + quad * 4;
            const int n = n0 + wn * 32 + ni * 16 + c16;
            const float b0 = bc[n];
            #pragma unroll
            for (int r = 0; r < 4; ++r)
                dout[(size_t)(m + r) * 1024 + n] = acc[mi][ni][r] + b0;
        }
    }
}

// ---------------------------------------------------------------------------
// Fused relative attention, 64-row tiles, 1024 threads (16 waves).
// Logits in LDS as bf16 [64][1024] = 128 KiB; XOR swizzle at 16B granularity.
// Phases 2/4: 16-way column split (4 t-iters/wave). Phase 6: 4 d-tiles x
// 4 k-quarters with 3-partial LDS reduce (reuses dead logits region).
// Fixed-shift softmax fused into AC pass; deferred normalization after PV.
// ---------------------------------------------------------------------------
__device__ __forceinline__ int lidx16(int row, int c) {
    return (row << 10) + ((((c >> 3) ^ row) << 3) | (c & 7));
}

__global__ __launch_bounds__(1024) void attn_kernel(
    const __hip_bfloat16* __restrict__ Qu,   // [4096][1024] (q+bq+u)
    const __hip_bfloat16* __restrict__ Kb,   // [4096][1024]
    const __hip_bfloat16* __restrict__ Posb, // [4096][1024] bf16 pos
    const __hip_bfloat16* __restrict__ Vt,   // [bh*64+d][s]
    const float* __restrict__ uvec, const float* __restrict__ vvec,
    __hip_bfloat16* __restrict__ O)          // [4096][1024]
{
    __shared__ __hip_bfloat16 Ls[64 * 1024];   // 128 KiB
    __shared__ float q2s[64];
    __shared__ float Wsum[64 * 16];            // per-(row, wave) partial sums
    __shared__ float rs[64];                   // per-row 1/sum

    const int tid  = threadIdx.x;
    const int lane = tid & 63, w = tid >> 6;   // w in [0,16)
    const int quad = lane >> 4, c16 = lane & 15;
    const int i0 = blockIdx.x * 64;
    const int bh = blockIdx.y;
    const int b = bh >> 4, h = bh & 15;
    const size_t headoff = (size_t)h * 64;
    const size_t tokbase = (size_t)b * 1024;
    const int j2 = i0 + 64;

    // q2s = (q+v) row j2 (fp32), for phase 3.
    if (tid < 64) {
        float val = 0.f;
        if (j2 < 1024)
            val = b2f(__builtin_bit_cast(__bf16,
                      Qu[(tokbase + j2) * 1024 + headoff + tid])) +
                  (vvec[tid] - uvec[tid]);
        q2s[tid] = val;
    }
    __syncthreads();

    // Phase 1: the rel-shift leaves exactly one zero per row, at c = i+1.
    if (tid < 64) {
        const int i = i0 + tid;
        if (i + 1 < 1024) Ls[lidx16(tid, i + 1)] = __float2bfloat16(0.f);
    }

    // Per-group Qu fragment pointers (group g = rows i0+g*16 .. +15).
    const __hip_bfloat16* qup0 =
        Qu + (tokbase + i0 + c16) * 1024 + headoff + quad * 8;

    // Phase 2: BD_raw = (q+v)·r^T for 64 rows, scattered through rel-shift.
    // bd_raw row j, col l -> out row j   at c = l+j-1023  (l >= 1023-j)
    //                     -> out row j-1 at c = l+j+1     (l <= 1022-j)
    {
        bf16x8 a[4][2];
        #pragma unroll
        for (int g = 0; g < 4; ++g) {
            a[g][0] = ldg8(qup0 + (size_t)g * 16 * 1024);
            a[g][1] = ldg8(qup0 + (size_t)g * 16 * 1024 + 32);
            #pragma unroll
            for (int j = 0; j < 8; ++j) {
                const int d = quad * 8 + j;
                a[g][0][j] = f2b(b2f(a[g][0][j]) + (vvec[d] - uvec[d]));
                a[g][1][j] = f2b(b2f(a[g][1][j]) + (vvec[d + 32] - uvec[d + 32]));
            }
        }
        for (int t = 0; t < 4; ++t) {
            const int l0 = w * 64 + t * 16;
            const __hip_bfloat16* rp =
                Posb + (tokbase + l0 + c16) * 1024 + headoff + quad * 8;
            const bf16x8 r0 = ldg8(rp);
            const bf16x8 r1 = ldg8(rp + 32);
            const int l = l0 + c16;
            #pragma unroll
            for (int g = 0; g < 4; ++g) {
                f32x4 c = (f32x4){0.f, 0.f, 0.f, 0.f};
                c = MFMA16(a[g][0], r0, c);
                c = MFMA16(a[g][1], r1, c);
                #pragma unroll
                for (int r = 0; r < 4; ++r) {
                    const int jl = g * 16 + quad * 4 + r;  // local bd_raw row
                    const int j  = i0 + jl;
                    const __bf16 val = f2b(c[r]);
                    if (l >= 1023 - j) Ls[lidx16(jl, l + j - 1023)] =
                        __builtin_bit_cast(__hip_bfloat16, val);
                    if (jl >= 1 && l <= 1022 - j) Ls[lidx16(jl - 1, l + j + 1)] =
                        __builtin_bit_cast(__hip_bfloat16, val);
                }
            }
        }
    }

    // Phase 3: extra bd_raw row j2 = i0+64 feeds local row 63 at c >= i0+65.
    if (j2 < 1024) {
        for (int c = i0 + 65 + tid; c < 1024; c += 1024) {
            const int l = c - i0 - 65;
            const __hip_bfloat16* rp = Posb + (tokbase + l) * 1024 + headoff;
            float s = 0.f;
            #pragma unroll
            for (int d8 = 0; d8 < 8; ++d8) {
                const bf16x8 rv = ldg8(rp + d8 * 8);
                #pragma unroll
                for (int j = 0; j < 8; ++j)
                    s += q2s[d8 * 8 + j] * b2f(rv[j]);
            }
            Ls[lidx16(63, c)] = __float2bfloat16(s);
        }
    }
    __syncthreads();

    // Phase 4: AC = (q+u)·k^T; fused P = exp2((bd+ac)*log2e/32 - 4*log2e)
    // (= exp(logit - 4); softmax shift-invariance + bounded logits).
    {
        bf16x8 au[4][2];
        #pragma unroll
        for (int g = 0; g < 4; ++g) {
            au[g][0] = ldg8(qup0 + (size_t)g * 16 * 1024);
            au[g][1] = ldg8(qup0 + (size_t)g * 16 * 1024 + 32);
        }
        const float C1 = 1.44269504f * 0.03125f;   // log2(e) * SCALE
        const float C2 = -5.77078016f;             // -4 * log2(e)
        float sums[4][4] = {};
        for (int t = 0; t < 4; ++t) {
            const int c0 = w * 64 + t * 16;
            const __hip_bfloat16* kp =
                Kb + (tokbase + c0 + c16) * 1024 + headoff + quad * 8;
            const bf16x8 k0 = ldg8(kp);
            const bf16x8 k1 = ldg8(kp + 32);
            const int cc = c0 + c16;
            #pragma unroll
            for (int g = 0; g < 4; ++g) {
                f32x4 c = (f32x4){0.f, 0.f, 0.f, 0.f};
                c = MFMA16(au[g][0], k0, c);
                c = MFMA16(au[g][1], k1, c);
                #pragma unroll
                for (int r = 0; r < 4; ++r) {
                    const int il = g * 16 + quad * 4 + r;
                    const int idx = lidx16(il, cc);
                    const float lg = __bfloat162float(Ls[idx]) + c[r];
                    const float p = __builtin_amdgcn_exp2f(fmaf(lg, C1, C2));
                    sums[g][r] += p;
                    Ls[idx] = __float2bfloat16(p);
                }
            }
        }
        #pragma unroll
        for (int g = 0; g < 4; ++g)
            #pragma unroll
            for (int r = 0; r < 4; ++r) {
                float s = sums[g][r];
                s += __shfl_xor(s, 1);
                s += __shfl_xor(s, 2);
                s += __shfl_xor(s, 4);
                s += __shfl_xor(s, 8);
                if (c16 == 0) Wsum[(g * 16 + quad * 4 + r) * 16 + w] = s;
            }
    }
    __syncthreads();

    if (tid < 64) {
        float s = 0.f;
        #pragma unroll
        for (int k = 0; k < 16; ++k) s += Wsum[tid * 16 + k];
        rs[tid] = 1.f / s;
    }
    __syncthreads();

    // Phase 6: O = (P @ V) * rinv for all 4 row groups.
    // Wave w: d-tile d0=(w&3)*16, k-quarter kh=w>>2 (256 cols each).
    {
        const int d0 = (w & 3) * 16;
        const int kh = w >> 2;
        const __hip_bfloat16* vp =
            Vt + ((size_t)bh * 64 + d0 + c16) * 1024 + quad * 8;
        f32x4 acc[4] = {};
        for (int kk = kh * 256; kk < kh * 256 + 256; kk += 32) {
            const bf16x8 vld = ldg8(vp + kk);
            #pragma unroll
            for (int g = 0; g < 4; ++g) {
                const bf16x8 p =
                    *(const bf16x8*)&Ls[lidx16(g * 16 + c16, kk + quad * 8)];
                acc[g] = MFMA16(p, vld, acc[g]);
            }
        }
        __syncthreads();   // all P reads done; logits LDS now reusable
        float* Lf = (float*)Ls;
        if (kh != 0) {
            const int sbase = ((kh - 1) * 4 + (w & 3)) * 1024;
            #pragma unroll
            for (int g = 0; g < 4; ++g)
                #pragma unroll
                for (int r = 0; r < 4; ++r)
                    Lf[sbase + g * 256 + (quad * 4 + r) * 16 + c16] = acc[g][r];
        }
        __syncthreads();
        if (kh == 0) {
            #pragma unroll
            for (int g = 0; g < 4; ++g)
                #pragma unroll
                for (int r = 0; r < 4; ++r) {
                    const int il = g * 16 + quad * 4 + r;
                    float val = acc[g][r];
                    #pragma unroll
                    for (int q = 1; q < 4; ++q)
                        val += Lf[((q - 1) * 4 + (w & 3)) * 1024 + g * 256 +
                                  (quad * 4 + r) * 16 + c16];
                    val *= rs[il];
                    const int i = i0 + il;
                    const int d = d0 + c16;
                    O[(tokbase + i) * 1024 + headoff + d] = __float2bfloat16(val);
                }
        }
    }
}

// ---------------------------------------------------------------------------
extern "C" void kernel_launch(void* const* d_in, const int* in_sizes, int n_in,
                              void* d_out, int out_size, void* d_ws, size_t ws_size,
                              hipStream_t stream)
{
    const float* x   = (const float*)d_in[0];
    const float* u   = (const float*)d_in[1];
    const float* v   = (const float*)d_in[2];
    const float* pos = (const float*)d_in[3];
    const float* Wq  = (const float*)d_in[4];
    const float* bq  = (const float*)d_in[5];
    const float* Wk  = (const float*)d_in[6];
    const float* bk  = (const float*)d_in[7];
    const float* Wv  = (const float*)d_in[8];
    const float* bv  = (const float*)d_in[9];
    const float* Wc  = (const float*)d_in[10];
    const float* bc  = (const float*)d_in[11];

    const size_t MB = (size_t)1 << 20;
    char* ws = (char*)d_ws;
    __hip_bfloat16* Qu    = (__hip_bfloat16*)(ws + 0 * MB);
    __hip_bfloat16* Kb    = (__hip_bfloat16*)(ws + 8 * MB);
    __hip_bfloat16* Vt    = (__hip_bfloat16*)(ws + 16 * MB);
    __hip_bfloat16* xb    = (__hip_bfloat16*)(ws + 24 * MB);  // aliased w/ O
    __hip_bfloat16* O     = (__hip_bfloat16*)(ws + 24 * MB);  // x dead after QKV
    __hip_bfloat16* Posb  = (__hip_bfloat16*)(ws + 32 * MB);
    __hip_bfloat16* Wqkvb = (__hip_bfloat16*)(ws + 40 * MB);
    __hip_bfloat16* Wcb   = (__hip_bfloat16*)(ws + 46 * MB);

    cvt_kernel<<<6144, 256, 0, stream>>>(x, pos, Wq, Wk, Wv, Wc,
                                         xb, Posb, Wqkvb, Wcb);

    gemm_qkv<<<dim3(24, 32), dim3(256), 0, stream>>>(
        xb, Wqkvb, bq, bk, bv, u, Qu, Kb, Vt);

    attn_kernel<<<dim3(16, 64), dim3(1024), 0, stream>>>(
        Qu, Kb, Posb, Vt, u, v, O);

    gemm_fin<<<dim3(16, 32), dim3(256), 0, stream>>>(
        O, Wcb, (float*)d_out, bc);
}

// Round 13
// 317.712 us; speedup vs baseline: 1.0018x; 1.0018x over previous
//
#include <hip/hip_runtime.h>
#include <hip/hip_bf16.h>

// RelAttention (Transformer-XL style) on MI355X.
// fp32 in/out; internal bf16 MFMA w/ fp32 accum.
// B=4, S=1024, D=1024, H=16, DH=64, BH=64. SCALE = 1/32.
//
// Pipeline: cvt -> fused QKV GEMM (m97-style) -> fused rel-attention
// (64-row tiles, 1024 threads, launch_bounds(1024,4) = honest 128-reg
// budget for exactly 1 block/CU, fixed-shift softmax fused into AC pass,
// deferred normalization) -> final GEMM (128x64 tiles).

typedef __bf16 bf16x8 __attribute__((ext_vector_type(8)));
typedef float  f32x4  __attribute__((ext_vector_type(4)));
typedef unsigned short u16x4 __attribute__((ext_vector_type(4)));

struct alignas(16) U128 { unsigned long long lo, hi; };

__device__ __forceinline__ bf16x8 ldg8(const __hip_bfloat16* p) {
    U128 u = *reinterpret_cast<const U128*>(p);
    return __builtin_bit_cast(bf16x8, u);
}

__device__ __forceinline__ __bf16 f2b(float f) {
    __hip_bfloat16 h = __float2bfloat16(f);
    return __builtin_bit_cast(__bf16, h);
}
__device__ __forceinline__ unsigned short f2bu(float f) {
    __hip_bfloat16 h = __float2bfloat16(f);
    return __builtin_bit_cast(unsigned short, h);
}
__device__ __forceinline__ float b2f(__bf16 b) {
    __hip_bfloat16 h = __builtin_bit_cast(__hip_bfloat16, b);
    return __bfloat162float(h);
}

__device__ __forceinline__ bf16x8 ldg8cvt(const float* p) {
    f32x4 a = *reinterpret_cast<const f32x4*>(p);
    f32x4 b = *reinterpret_cast<const f32x4*>(p + 4);
    bf16x8 r;
    r[0] = f2b(a[0]); r[1] = f2b(a[1]); r[2] = f2b(a[2]); r[3] = f2b(a[3]);
    r[4] = f2b(b[0]); r[5] = f2b(b[1]); r[6] = f2b(b[2]); r[7] = f2b(b[3]);
    return r;
}

#define MFMA16(a, b, c) __builtin_amdgcn_mfma_f32_16x16x32_bf16((a), (b), (c), 0, 0, 0)

__device__ __forceinline__ void gll16(const __hip_bfloat16* g, void* lds_wave_base) {
    __builtin_amdgcn_global_load_lds(
        (const __attribute__((address_space(1))) void*)g,
        (__attribute__((address_space(3))) void*)lds_wave_base,
        16, 0, 0);
}

// ---------------------------------------------------------------------------
// fp32 -> bf16: x(4M), pos(4M), Wq/Wk/Wv(3M stacked), Wc(1M) = 12M elems.
// ---------------------------------------------------------------------------
__global__ __launch_bounds__(256) void cvt_kernel(
    const float* __restrict__ x,  const float* __restrict__ pos,
    const float* __restrict__ wq, const float* __restrict__ wk,
    const float* __restrict__ wv, const float* __restrict__ wc,
    __hip_bfloat16* __restrict__ xb, __hip_bfloat16* __restrict__ posb,
    __hip_bfloat16* __restrict__ wqkvb, __hip_bfloat16* __restrict__ wcb)
{
    const size_t base = ((size_t)blockIdx.x * 256 + threadIdx.x) * 8;
    const size_t M1 = (size_t)1 << 20;
    const float* src; __hip_bfloat16* dst; size_t o;
    if (base < 4*M1)        { src = x;   dst = xb;           o = base; }
    else if (base < 8*M1)   { src = pos; dst = posb;         o = base - 4*M1; }
    else if (base < 9*M1)   { src = wq;  dst = wqkvb;        o = base - 8*M1; }
    else if (base < 10*M1)  { src = wk;  dst = wqkvb + M1;   o = base - 9*M1; }
    else if (base < 11*M1)  { src = wv;  dst = wqkvb + 2*M1; o = base - 10*M1; }
    else                    { src = wc;  dst = wcb;          o = base - 11*M1; }
    *(bf16x8*)(dst + o) = ldg8cvt(src + o);
}

// ---------------------------------------------------------------------------
// QKV GEMM (m97-style): C[m][n] = sum_k A[m][k]*Bm[n][k], Bm=[3072][1024].
// n<1024 -> Qu = C+bq+u; <2048 -> Kb = C+bk; else Vt head-transposed = C+bv.
// ---------------------------------------------------------------------------
__global__ __launch_bounds__(256) void gemm_qkv(
    const __hip_bfloat16* __restrict__ A,
    const __hip_bfloat16* __restrict__ Bm,
    const float* __restrict__ bq, const float* __restrict__ bk,
    const float* __restrict__ bv, const float* __restrict__ u,
    __hip_bfloat16* __restrict__ Qu,
    __hip_bfloat16* __restrict__ Kb, __hip_bfloat16* __restrict__ Vt)
{
    __shared__ __hip_bfloat16 As[128 * 32];
    __shared__ __hip_bfloat16 Bs[128 * 32];

    const int tid  = threadIdx.x;
    const int lane = tid & 63, w = tid >> 6;
    const int quad = lane >> 4, c16 = lane & 15;
    const int wm = w >> 1, wn = w & 1;
    const int m0 = blockIdx.y * 128;
    const int n0 = blockIdx.x * 128;

    const int srow = w * 16 + (lane >> 2);
    const int scol = (lane & 3) * 8;
    const __hip_bfloat16* gA0 = A  + (size_t)(m0 + srow) * 1024 + scol;
    const __hip_bfloat16* gA1 = gA0 + (size_t)64 * 1024;
    const __hip_bfloat16* gB0 = Bm + (size_t)(n0 + srow) * 1024 + scol;
    const __hip_bfloat16* gB1 = gB0 + (size_t)64 * 1024;
    char* ldsA0 = (char*)As + (w << 10);
    char* ldsA1 = ldsA0 + 4096;
    char* ldsB0 = (char*)Bs + (w << 10);
    char* ldsB1 = ldsB0 + 4096;

    f32x4 acc[4][4] = {};

    for (int k0 = 0; k0 < 1024; k0 += 32) {
        gll16(gA0 + k0, ldsA0);
        gll16(gA1 + k0, ldsA1);
        gll16(gB0 + k0, ldsB0);
        gll16(gB1 + k0, ldsB1);
        __syncthreads();

        bf16x8 af[4], bfr[4];
        #pragma unroll
        for (int i = 0; i < 4; ++i) {
            af[i]  = *(const bf16x8*)&As[(wm * 64 + i * 16 + c16) * 32 + quad * 8];
            bfr[i] = *(const bf16x8*)&Bs[(wn * 64 + i * 16 + c16) * 32 + quad * 8];
        }
        #pragma unroll
        for (int mi = 0; mi < 4; ++mi)
            #pragma unroll
            for (int ni = 0; ni < 4; ++ni)
                acc[mi][ni] = MFMA16(af[mi], bfr[ni], acc[mi][ni]);
        __syncthreads();
    }

    #pragma unroll
    for (int mi = 0; mi < 4; ++mi) {
        #pragma unroll
        for (int ni = 0; ni < 4; ++ni) {
            const int m = m0 + wm * 64 + mi * 16 + quad * 4;  // +r
            const int n = n0 + wn * 64 + ni * 16 + c16;
            if (n < 1024) {
                const float b0 = bq[n] + u[n & 63];
                #pragma unroll
                for (int r = 0; r < 4; ++r)
                    Qu[(size_t)(m + r) * 1024 + n] =
                        __float2bfloat16(acc[mi][ni][r] + b0);
            } else if (n < 2048) {
                const int nn = n - 1024;
                const float b0 = bk[nn];
                #pragma unroll
                for (int r = 0; r < 4; ++r)
                    Kb[(size_t)(m + r) * 1024 + nn] =
                        __float2bfloat16(acc[mi][ni][r] + b0);
            } else {
                const int nn = n - 2048;
                const float b0 = bv[nn];
                const int d = nn & 63, hh = nn >> 6;
                const int bb = m >> 10, s = m & 1023;
                u16x4 pk;
                #pragma unroll
                for (int r = 0; r < 4; ++r)
                    pk[r] = f2bu(acc[mi][ni][r] + b0);
                *(u16x4*)&Vt[(((size_t)(bb * 16 + hh) * 64 + d) << 10) + s] = pk;
            }
        }
    }
}

// ---------------------------------------------------------------------------
// Final GEMM, 128x64 tiles (grid 16x32 = 512 blocks -> 2 blocks/CU).
// Wave (2x2): 64x32 sub-tile, acc[4][2] -> 8 MFMA / 6 fragment loads.
// ---------------------------------------------------------------------------
__global__ __launch_bounds__(256) void gemm_fin(
    const __hip_bfloat16* __restrict__ A,
    const __hip_bfloat16* __restrict__ Bm,
    float* __restrict__ dout, const float* __restrict__ bc)
{
    __shared__ __hip_bfloat16 As[128 * 32];   // 8 KiB
    __shared__ __hip_bfloat16 Bs[64 * 32];    // 4 KiB

    const int tid  = threadIdx.x;
    const int lane = tid & 63, w = tid >> 6;
    const int quad = lane >> 4, c16 = lane & 15;
    const int wm = w >> 1, wn = w & 1;
    const int m0 = blockIdx.y * 128;
    const int n0 = blockIdx.x * 64;

    const int srow = w * 16 + (lane >> 2);
    const int scol = (lane & 3) * 8;
    const __hip_bfloat16* gA0 = A  + (size_t)(m0 + srow) * 1024 + scol;
    const __hip_bfloat16* gA1 = gA0 + (size_t)64 * 1024;
    const __hip_bfloat16* gB0 = Bm + (size_t)(n0 + srow) * 1024 + scol;
    char* ldsA0 = (char*)As + (w << 10);
    char* ldsA1 = ldsA0 + 4096;
    char* ldsB0 = (char*)Bs + (w << 10);

    f32x4 acc[4][2] = {};

    for (int k0 = 0; k0 < 1024; k0 += 32) {
        gll16(gA0 + k0, ldsA0);
        gll16(gA1 + k0, ldsA1);
        gll16(gB0 + k0, ldsB0);
        __syncthreads();

        bf16x8 af[4], bfr[2];
        #pragma unroll
        for (int i = 0; i < 4; ++i)
            af[i] = *(const bf16x8*)&As[(wm * 64 + i * 16 + c16) * 32 + quad * 8];
        #pragma unroll
        for (int i = 0; i < 2; ++i)
            bfr[i] = *(const bf16x8*)&Bs[(wn * 32 + i * 16 + c16) * 32 + quad * 8];
        #pragma unroll
        for (int mi = 0; mi < 4; ++mi)
            #pragma unroll
            for (int ni = 0; ni < 2; ++ni)
                acc[mi][ni] = MFMA16(af[mi], bfr[ni], acc[mi][ni]);
        __syncthreads();
    }

    #pragma unroll
    for (int mi = 0; mi < 4; ++mi) {
        #pragma unroll
        for (int ni = 0; ni < 2; ++ni) {
            const int m = m0 + wm * 64 + mi * 16 + quad * 4;
            const int n = n0 + wn * 32 + ni * 16 + c16;
            const float b0 = bc[n];
            #pragma unroll
            for (int r = 0; r < 4; ++r)
                dout[(size_t)(m + r) * 1024 + n] = acc[mi][ni][r] + b0;
        }
    }
}

// ---------------------------------------------------------------------------
// Fused relative attention, 64-row tiles, 1024 threads (16 waves).
// launch_bounds(1024,4): 4 waves/SIMD = exactly one 1024-thr block/CU ->
// honest 128-VGPR budget (natural demand ~124, r11) -> no scratch spill.
// Logits in LDS as bf16 [64][1024] = 128 KiB; XOR swizzle at 16B granularity.
// Phases 2/4: 16-way column split. Phase 6: 4 d-tiles x 4 k-quarters with
// 3-partial LDS reduce. Fixed-shift softmax fused into AC pass; deferred
// normalization after PV.
// ---------------------------------------------------------------------------
__device__ __forceinline__ int lidx16(int row, int c) {
    return (row << 10) + ((((c >> 3) ^ row) << 3) | (c & 7));
}

__global__ __launch_bounds__(1024, 4) void attn_kernel(
    const __hip_bfloat16* __restrict__ Qu,   // [4096][1024] (q+bq+u)
    const __hip_bfloat16* __restrict__ Kb,   // [4096][1024]
    const __hip_bfloat16* __restrict__ Posb, // [4096][1024] bf16 pos
    const __hip_bfloat16* __restrict__ Vt,   // [bh*64+d][s]
    const float* __restrict__ uvec, const float* __restrict__ vvec,
    __hip_bfloat16* __restrict__ O)          // [4096][1024]
{
    __shared__ __hip_bfloat16 Ls[64 * 1024];   // 128 KiB
    __shared__ float q2s[64];
    __shared__ float Wsum[64 * 16];            // per-(row, wave) partial sums
    __shared__ float rs[64];                   // per-row 1/sum

    const int tid  = threadIdx.x;
    const int lane = tid & 63, w = tid >> 6;   // w in [0,16)
    const int quad = lane >> 4, c16 = lane & 15;
    const int i0 = blockIdx.x * 64;
    const int bh = blockIdx.y;
    const int b = bh >> 4, h = bh & 15;
    const size_t headoff = (size_t)h * 64;
    const size_t tokbase = (size_t)b * 1024;
    const int j2 = i0 + 64;

    // q2s = (q+v) row j2 (fp32), for phase 3.
    if (tid < 64) {
        float val = 0.f;
        if (j2 < 1024)
            val = b2f(__builtin_bit_cast(__bf16,
                      Qu[(tokbase + j2) * 1024 + headoff + tid])) +
                  (vvec[tid] - uvec[tid]);
        q2s[tid] = val;
    }
    __syncthreads();

    // Phase 1: the rel-shift leaves exactly one zero per row, at c = i+1.
    if (tid < 64) {
        const int i = i0 + tid;
        if (i + 1 < 1024) Ls[lidx16(tid, i + 1)] = __float2bfloat16(0.f);
    }

    // Per-group Qu fragment pointers (group g = rows i0+g*16 .. +15).
    const __hip_bfloat16* qup0 =
        Qu + (tokbase + i0 + c16) * 1024 + headoff + quad * 8;

    // Phase 2: BD_raw = (q+v)·r^T for 64 rows, scattered through rel-shift.
    // bd_raw row j, col l -> out row j   at c = l+j-1023  (l >= 1023-j)
    //                     -> out row j-1 at c = l+j+1     (l <= 1022-j)
    {
        bf16x8 a[4][2];
        #pragma unroll
        for (int g = 0; g < 4; ++g) {
            a[g][0] = ldg8(qup0 + (size_t)g * 16 * 1024);
            a[g][1] = ldg8(qup0 + (size_t)g * 16 * 1024 + 32);
            #pragma unroll
            for (int j = 0; j < 8; ++j) {
                const int d = quad * 8 + j;
                a[g][0][j] = f2b(b2f(a[g][0][j]) + (vvec[d] - uvec[d]));
                a[g][1][j] = f2b(b2f(a[g][1][j]) + (vvec[d + 32] - uvec[d + 32]));
            }
        }
        for (int t = 0; t < 4; ++t) {
            const int l0 = w * 64 + t * 16;
            const __hip_bfloat16* rp =
                Posb + (tokbase + l0 + c16) * 1024 + headoff + quad * 8;
            const bf16x8 r0 = ldg8(rp);
            const bf16x8 r1 = ldg8(rp + 32);
            const int l = l0 + c16;
            #pragma unroll
            for (int g = 0; g < 4; ++g) {
                f32x4 c = (f32x4){0.f, 0.f, 0.f, 0.f};
                c = MFMA16(a[g][0], r0, c);
                c = MFMA16(a[g][1], r1, c);
                #pragma unroll
                for (int r = 0; r < 4; ++r) {
                    const int jl = g * 16 + quad * 4 + r;  // local bd_raw row
                    const int j  = i0 + jl;
                    const __bf16 val = f2b(c[r]);
                    if (l >= 1023 - j) Ls[lidx16(jl, l + j - 1023)] =
                        __builtin_bit_cast(__hip_bfloat16, val);
                    if (jl >= 1 && l <= 1022 - j) Ls[lidx16(jl - 1, l + j + 1)] =
                        __builtin_bit_cast(__hip_bfloat16, val);
                }
            }
        }
    }

    // Phase 3: extra bd_raw row j2 = i0+64 feeds local row 63 at c >= i0+65.
    if (j2 < 1024) {
        for (int c = i0 + 65 + tid; c < 1024; c += 1024) {
            const int l = c - i0 - 65;
            const __hip_bfloat16* rp = Posb + (tokbase + l) * 1024 + headoff;
            float s = 0.f;
            #pragma unroll
            for (int d8 = 0; d8 < 8; ++d8) {
                const bf16x8 rv = ldg8(rp + d8 * 8);
                #pragma unroll
                for (int j = 0; j < 8; ++j)
                    s += q2s[d8 * 8 + j] * b2f(rv[j]);
            }
            Ls[lidx16(63, c)] = __float2bfloat16(s);
        }
    }
    __syncthreads();

    // Phase 4: AC = (q+u)·k^T; fused P = exp2((bd+ac)*log2e/32 - 4*log2e)
    // (= exp(logit - 4); softmax shift-invariance + bounded logits).
    {
        bf16x8 au[4][2];
        #pragma unroll
        for (int g = 0; g < 4; ++g) {
            au[g][0] = ldg8(qup0 + (size_t)g * 16 * 1024);
            au[g][1] = ldg8(qup0 + (size_t)g * 16 * 1024 + 32);
        }
        const float C1 = 1.44269504f * 0.03125f;   // log2(e) * SCALE
        const float C2 = -5.77078016f;             // -4 * log2(e)
        float sums[4][4] = {};
        for (int t = 0; t < 4; ++t) {
            const int c0 = w * 64 + t * 16;
            const __hip_bfloat16* kp =
                Kb + (tokbase + c0 + c16) * 1024 + headoff + quad * 8;
            const bf16x8 k0 = ldg8(kp);
            const bf16x8 k1 = ldg8(kp + 32);
            const int cc = c0 + c16;
            #pragma unroll
            for (int g = 0; g < 4; ++g) {
                f32x4 c = (f32x4){0.f, 0.f, 0.f, 0.f};
                c = MFMA16(au[g][0], k0, c);
                c = MFMA16(au[g][1], k1, c);
                #pragma unroll
                for (int r = 0; r < 4; ++r) {
                    const int il = g * 16 + quad * 4 + r;
                    const int idx = lidx16(il, cc);
                    const float lg = __bfloat162float(Ls[idx]) + c[r];
                    const float p = __builtin_amdgcn_exp2f(fmaf(lg, C1, C2));
                    sums[g][r] += p;
                    Ls[idx] = __float2bfloat16(p);
                }
            }
        }
        #pragma unroll
        for (int g = 0; g < 4; ++g)
            #pragma unroll
            for (int r = 0; r < 4; ++r) {
                float s = sums[g][r];
                s += __shfl_xor(s, 1);
                s += __shfl_xor(s, 2);
                s += __shfl_xor(s, 4);
                s += __shfl_xor(s, 8);
                if (c16 == 0) Wsum[(g * 16 + quad * 4 + r) * 16 + w] = s;
            }
    }
    __syncthreads();

    if (tid < 64) {
        float s = 0.f;
        #pragma unroll
        for (int k = 0; k < 16; ++k) s += Wsum[tid * 16 + k];
        rs[tid] = 1.f / s;
    }
    __syncthreads();

    // Phase 6: O = (P @ V) * rinv for all 4 row groups.
    // Wave w: d-tile d0=(w&3)*16, k-quarter kh=w>>2 (256 cols each).
    {
        const int d0 = (w & 3) * 16;
        const int kh = w >> 2;
        const __hip_bfloat16* vp =
            Vt + ((size_t)bh * 64 + d0 + c16) * 1024 + quad * 8;
        f32x4 acc[4] = {};
        for (int kk = kh * 256; kk < kh * 256 + 256; kk += 32) {
            const bf16x8 vld = ldg8(vp + kk);
            #pragma unroll
            for (int g = 0; g < 4; ++g) {
                const bf16x8 p =
                    *(const bf16x8*)&Ls[lidx16(g * 16 + c16, kk + quad * 8)];
                acc[g] = MFMA16(p, vld, acc[g]);
            }
        }
        __syncthreads();   // all P reads done; logits LDS now reusable
        float* Lf = (float*)Ls;
        if (kh != 0) {
            const int sbase = ((kh - 1) * 4 + (w & 3)) * 1024;
            #pragma unroll
            for (int g = 0; g < 4; ++g)
                #pragma unroll
                for (int r = 0; r < 4; ++r)
                    Lf[sbase + g * 256 + (quad * 4 + r) * 16 + c16] = acc[g][r];
        }
        __syncthreads();
        if (kh == 0) {
            #pragma unroll
            for (int g = 0; g < 4; ++g)
                #pragma unroll
                for (int r = 0; r < 4; ++r) {
                    const int il = g * 16 + quad * 4 + r;
                    float val = acc[g][r];
                    #pragma unroll
                    for (int q = 1; q < 4; ++q)
                        val += Lf[((q - 1) * 4 + (w & 3)) * 1024 + g * 256 +
                                  (quad * 4 + r) * 16 + c16];
                    val *= rs[il];
                    const int i = i0 + il;
                    const int d = d0 + c16;
                    O[(tokbase + i) * 1024 + headoff + d] = __float2bfloat16(val);
                }
        }
    }
}

// ---------------------------------------------------------------------------
extern "C" void kernel_launch(void* const* d_in, const int* in_sizes, int n_in,
                              void* d_out, int out_size, void* d_ws, size_t ws_size,
                              hipStream_t stream)
{
    const float* x   = (const float*)d_in[0];
    const float* u   = (const float*)d_in[1];
    const float* v   = (const float*)d_in[2];
    const float* pos = (const float*)d_in[3];
    const float* Wq  = (const float*)d_in[4];
    const float* bq  = (const float*)d_in[5];
    const float* Wk  = (const float*)d_in[6];
    const float* bk  = (const float*)d_in[7];
    const float* Wv  = (const float*)d_in[8];
    const float* bv  = (const float*)d_in[9];
    const float* Wc  = (const float*)d_in[10];
    const float* bc  = (const float*)d_in[11];

    const size_t MB = (size_t)1 << 20;
    char* ws = (char*)d_ws;
    __hip_bfloat16* Qu    = (__hip_bfloat16*)(ws + 0 * MB);
    __hip_bfloat16* Kb    = (__hip_bfloat16*)(ws + 8 * MB);
    __hip_bfloat16* Vt    = (__hip_bfloat16*)(ws + 16 * MB);
    __hip_bfloat16* xb    = (__hip_bfloat16*)(ws + 24 * MB);  // aliased w/ O
    __hip_bfloat16* O     = (__hip_bfloat16*)(ws + 24 * MB);  // x dead after QKV
    __hip_bfloat16* Posb  = (__hip_bfloat16*)(ws + 32 * MB);
    __hip_bfloat16* Wqkvb = (__hip_bfloat16*)(ws + 40 * MB);
    __hip_bfloat16* Wcb   = (__hip_bfloat16*)(ws + 46 * MB);

    cvt_kernel<<<6144, 256, 0, stream>>>(x, pos, Wq, Wk, Wv, Wc,
                                         xb, Posb, Wqkvb, Wcb);

    gemm_qkv<<<dim3(24, 32), dim3(256), 0, stream>>>(
        xb, Wqkvb, bq, bk, bv, u, Qu, Kb, Vt);

    attn_kernel<<<dim3(16, 64), dim3(1024), 0, stream>>>(
        Qu, Kb, Posb, Vt, u, v, O);

    gemm_fin<<<dim3(16, 32), dim3(256), 0, stream>>>(
        O, Wcb, (float*)d_out, bc);
}

// Round 14
// 298.309 us; speedup vs baseline: 1.0670x; 1.0650x over previous
//
#include <hip/hip_runtime.h>
#include <hip/hip_bf16.h>

// RelAttention (Transformer-XL style) on MI355X.
// fp32 in/out; internal bf16 MFMA w/ fp32 accum.
// B=4, S=1024, D=1024, H=16, DH=64, BH=64. SCALE = 1/32.
//
// Pipeline: cvt -> fused QKV GEMM (m97-style) -> fused rel-attention
// (64-row tiles, 512 thr — r11 structure; K fragments register-prefetched
// during phase 2 so phase 4 runs load-free; fixed-shift softmax fused into
// AC pass; deferred normalization) -> final GEMM (128x64 tiles).

typedef __bf16 bf16x8 __attribute__((ext_vector_type(8)));
typedef float  f32x4  __attribute__((ext_vector_type(4)));
typedef unsigned short u16x4 __attribute__((ext_vector_type(4)));

struct alignas(16) U128 { unsigned long long lo, hi; };

__device__ __forceinline__ bf16x8 ldg8(const __hip_bfloat16* p) {
    U128 u = *reinterpret_cast<const U128*>(p);
    return __builtin_bit_cast(bf16x8, u);
}

__device__ __forceinline__ __bf16 f2b(float f) {
    __hip_bfloat16 h = __float2bfloat16(f);
    return __builtin_bit_cast(__bf16, h);
}
__device__ __forceinline__ unsigned short f2bu(float f) {
    __hip_bfloat16 h = __float2bfloat16(f);
    return __builtin_bit_cast(unsigned short, h);
}
__device__ __forceinline__ float b2f(__bf16 b) {
    __hip_bfloat16 h = __builtin_bit_cast(__hip_bfloat16, b);
    return __bfloat162float(h);
}

__device__ __forceinline__ bf16x8 ldg8cvt(const float* p) {
    f32x4 a = *reinterpret_cast<const f32x4*>(p);
    f32x4 b = *reinterpret_cast<const f32x4*>(p + 4);
    bf16x8 r;
    r[0] = f2b(a[0]); r[1] = f2b(a[1]); r[2] = f2b(a[2]); r[3] = f2b(a[3]);
    r[4] = f2b(b[0]); r[5] = f2b(b[1]); r[6] = f2b(b[2]); r[7] = f2b(b[3]);
    return r;
}

#define MFMA16(a, b, c) __builtin_amdgcn_mfma_f32_16x16x32_bf16((a), (b), (c), 0, 0, 0)

__device__ __forceinline__ void gll16(const __hip_bfloat16* g, void* lds_wave_base) {
    __builtin_amdgcn_global_load_lds(
        (const __attribute__((address_space(1))) void*)g,
        (__attribute__((address_space(3))) void*)lds_wave_base,
        16, 0, 0);
}

// ---------------------------------------------------------------------------
// fp32 -> bf16: x(4M), pos(4M), Wq/Wk/Wv(3M stacked), Wc(1M) = 12M elems.
// ---------------------------------------------------------------------------
__global__ __launch_bounds__(256) void cvt_kernel(
    const float* __restrict__ x,  const float* __restrict__ pos,
    const float* __restrict__ wq, const float* __restrict__ wk,
    const float* __restrict__ wv, const float* __restrict__ wc,
    __hip_bfloat16* __restrict__ xb, __hip_bfloat16* __restrict__ posb,
    __hip_bfloat16* __restrict__ wqkvb, __hip_bfloat16* __restrict__ wcb)
{
    const size_t base = ((size_t)blockIdx.x * 256 + threadIdx.x) * 8;
    const size_t M1 = (size_t)1 << 20;
    const float* src; __hip_bfloat16* dst; size_t o;
    if (base < 4*M1)        { src = x;   dst = xb;           o = base; }
    else if (base < 8*M1)   { src = pos; dst = posb;         o = base - 4*M1; }
    else if (base < 9*M1)   { src = wq;  dst = wqkvb;        o = base - 8*M1; }
    else if (base < 10*M1)  { src = wk;  dst = wqkvb + M1;   o = base - 9*M1; }
    else if (base < 11*M1)  { src = wv;  dst = wqkvb + 2*M1; o = base - 10*M1; }
    else                    { src = wc;  dst = wcb;          o = base - 11*M1; }
    *(bf16x8*)(dst + o) = ldg8cvt(src + o);
}

// ---------------------------------------------------------------------------
// QKV GEMM (m97-style): C[m][n] = sum_k A[m][k]*Bm[n][k], Bm=[3072][1024].
// n<1024 -> Qu = C+bq+u; <2048 -> Kb = C+bk; else Vt head-transposed = C+bv.
// ---------------------------------------------------------------------------
__global__ __launch_bounds__(256) void gemm_qkv(
    const __hip_bfloat16* __restrict__ A,
    const __hip_bfloat16* __restrict__ Bm,
    const float* __restrict__ bq, const float* __restrict__ bk,
    const float* __restrict__ bv, const float* __restrict__ u,
    __hip_bfloat16* __restrict__ Qu,
    __hip_bfloat16* __restrict__ Kb, __hip_bfloat16* __restrict__ Vt)
{
    __shared__ __hip_bfloat16 As[128 * 32];
    __shared__ __hip_bfloat16 Bs[128 * 32];

    const int tid  = threadIdx.x;
    const int lane = tid & 63, w = tid >> 6;
    const int quad = lane >> 4, c16 = lane & 15;
    const int wm = w >> 1, wn = w & 1;
    const int m0 = blockIdx.y * 128;
    const int n0 = blockIdx.x * 128;

    const int srow = w * 16 + (lane >> 2);
    const int scol = (lane & 3) * 8;
    const __hip_bfloat16* gA0 = A  + (size_t)(m0 + srow) * 1024 + scol;
    const __hip_bfloat16* gA1 = gA0 + (size_t)64 * 1024;
    const __hip_bfloat16* gB0 = Bm + (size_t)(n0 + srow) * 1024 + scol;
    const __hip_bfloat16* gB1 = gB0 + (size_t)64 * 1024;
    char* ldsA0 = (char*)As + (w << 10);
    char* ldsA1 = ldsA0 + 4096;
    char* ldsB0 = (char*)Bs + (w << 10);
    char* ldsB1 = ldsB0 + 4096;

    f32x4 acc[4][4] = {};

    for (int k0 = 0; k0 < 1024; k0 += 32) {
        gll16(gA0 + k0, ldsA0);
        gll16(gA1 + k0, ldsA1);
        gll16(gB0 + k0, ldsB0);
        gll16(gB1 + k0, ldsB1);
        __syncthreads();

        bf16x8 af[4], bfr[4];
        #pragma unroll
        for (int i = 0; i < 4; ++i) {
            af[i]  = *(const bf16x8*)&As[(wm * 64 + i * 16 + c16) * 32 + quad * 8];
            bfr[i] = *(const bf16x8*)&Bs[(wn * 64 + i * 16 + c16) * 32 + quad * 8];
        }
        #pragma unroll
        for (int mi = 0; mi < 4; ++mi)
            #pragma unroll
            for (int ni = 0; ni < 4; ++ni)
                acc[mi][ni] = MFMA16(af[mi], bfr[ni], acc[mi][ni]);
        __syncthreads();
    }

    #pragma unroll
    for (int mi = 0; mi < 4; ++mi) {
        #pragma unroll
        for (int ni = 0; ni < 4; ++ni) {
            const int m = m0 + wm * 64 + mi * 16 + quad * 4;  // +r
            const int n = n0 + wn * 64 + ni * 16 + c16;
            if (n < 1024) {
                const float b0 = bq[n] + u[n & 63];
                #pragma unroll
                for (int r = 0; r < 4; ++r)
                    Qu[(size_t)(m + r) * 1024 + n] =
                        __float2bfloat16(acc[mi][ni][r] + b0);
            } else if (n < 2048) {
                const int nn = n - 1024;
                const float b0 = bk[nn];
                #pragma unroll
                for (int r = 0; r < 4; ++r)
                    Kb[(size_t)(m + r) * 1024 + nn] =
                        __float2bfloat16(acc[mi][ni][r] + b0);
            } else {
                const int nn = n - 2048;
                const float b0 = bv[nn];
                const int d = nn & 63, hh = nn >> 6;
                const int bb = m >> 10, s = m & 1023;
                u16x4 pk;
                #pragma unroll
                for (int r = 0; r < 4; ++r)
                    pk[r] = f2bu(acc[mi][ni][r] + b0);
                *(u16x4*)&Vt[(((size_t)(bb * 16 + hh) * 64 + d) << 10) + s] = pk;
            }
        }
    }
}

// ---------------------------------------------------------------------------
// Final GEMM, 128x64 tiles (grid 16x32 = 512 blocks -> 2 blocks/CU).
// ---------------------------------------------------------------------------
__global__ __launch_bounds__(256) void gemm_fin(
    const __hip_bfloat16* __restrict__ A,
    const __hip_bfloat16* __restrict__ Bm,
    float* __restrict__ dout, const float* __restrict__ bc)
{
    __shared__ __hip_bfloat16 As[128 * 32];   // 8 KiB
    __shared__ __hip_bfloat16 Bs[64 * 32];    // 4 KiB

    const int tid  = threadIdx.x;
    const int lane = tid & 63, w = tid >> 6;
    const int quad = lane >> 4, c16 = lane & 15;
    const int wm = w >> 1, wn = w & 1;
    const int m0 = blockIdx.y * 128;
    const int n0 = blockIdx.x * 64;

    const int srow = w * 16 + (lane >> 2);
    const int scol = (lane & 3) * 8;
    const __hip_bfloat16* gA0 = A  + (size_t)(m0 + srow) * 1024 + scol;
    const __hip_bfloat16* gA1 = gA0 + (size_t)64 * 1024;
    const __hip_bfloat16* gB0 = Bm + (size_t)(n0 + srow) * 1024 + scol;
    char* ldsA0 = (char*)As + (w << 10);
    char* ldsA1 = ldsA0 + 4096;
    char* ldsB0 = (char*)Bs + (w << 10);

    f32x4 acc[4][2] = {};

    for (int k0 = 0; k0 < 1024; k0 += 32) {
        gll16(gA0 + k0, ldsA0);
        gll16(gA1 + k0, ldsA1);
        gll16(gB0 + k0, ldsB0);
        __syncthreads();

        bf16x8 af[4], bfr[2];
        #pragma unroll
        for (int i = 0; i < 4; ++i)
            af[i] = *(const bf16x8*)&As[(wm * 64 + i * 16 + c16) * 32 + quad * 8];
        #pragma unroll
        for (int i = 0; i < 2; ++i)
            bfr[i] = *(const bf16x8*)&Bs[(wn * 32 + i * 16 + c16) * 32 + quad * 8];
        #pragma unroll
        for (int mi = 0; mi < 4; ++mi)
            #pragma unroll
            for (int ni = 0; ni < 2; ++ni)
                acc[mi][ni] = MFMA16(af[mi], bfr[ni], acc[mi][ni]);
        __syncthreads();
    }

    #pragma unroll
    for (int mi = 0; mi < 4; ++mi) {
        #pragma unroll
        for (int ni = 0; ni < 2; ++ni) {
            const int m = m0 + wm * 64 + mi * 16 + quad * 4;
            const int n = n0 + wn * 32 + ni * 16 + c16;
            const float b0 = bc[n];
            #pragma unroll
            for (int r = 0; r < 4; ++r)
                dout[(size_t)(m + r) * 1024 + n] = acc[mi][ni][r] + b0;
        }
    }
}

// ---------------------------------------------------------------------------
// Fused relative attention, 64-row tiles, 512 threads (8 waves) — r11
// structure. New: au held across phases (no phase-4 reload) and K fragments
// register-prefetched at the start of phase 2 (kf[8][2], issued before the
// phase-2 MFMA work) so phase 4 runs entirely out of registers.
// Logits in LDS as bf16 [64][1024] = 128 KiB; XOR swizzle at 16B granularity.
// Fixed-shift softmax fused into AC pass; deferred normalization after PV.
// ---------------------------------------------------------------------------
__device__ __forceinline__ int lidx16(int row, int c) {
    return (row << 10) + ((((c >> 3) ^ row) << 3) | (c & 7));
}

__global__ __launch_bounds__(512) void attn_kernel(
    const __hip_bfloat16* __restrict__ Qu,   // [4096][1024] (q+bq+u)
    const __hip_bfloat16* __restrict__ Kb,   // [4096][1024]
    const __hip_bfloat16* __restrict__ Posb, // [4096][1024] bf16 pos
    const __hip_bfloat16* __restrict__ Vt,   // [bh*64+d][s]
    const float* __restrict__ uvec, const float* __restrict__ vvec,
    __hip_bfloat16* __restrict__ O)          // [4096][1024]
{
    __shared__ __hip_bfloat16 Ls[64 * 1024];   // 128 KiB
    __shared__ float q2s[64];
    __shared__ float Wsum[64 * 8];             // per-(row, wave) partial sums
    __shared__ float rs[64];                   // per-row 1/sum

    const int tid  = threadIdx.x;
    const int lane = tid & 63, w = tid >> 6;   // w in [0,8)
    const int quad = lane >> 4, c16 = lane & 15;
    const int i0 = blockIdx.x * 64;
    const int bh = blockIdx.y;
    const int b = bh >> 4, h = bh & 15;
    const size_t headoff = (size_t)h * 64;
    const size_t tokbase = (size_t)b * 1024;
    const int j2 = i0 + 64;

    // q2s = (q+v) row j2 (fp32), for phase 3.
    if (tid < 64) {
        float val = 0.f;
        if (j2 < 1024)
            val = b2f(__builtin_bit_cast(__bf16,
                      Qu[(tokbase + j2) * 1024 + headoff + tid])) +
                  (vvec[tid] - uvec[tid]);
        q2s[tid] = val;
    }
    __syncthreads();

    // Phase 1: the rel-shift leaves exactly one zero per row, at c = i+1.
    if (tid < 64) {
        const int i = i0 + tid;
        if (i + 1 < 1024) Ls[lidx16(tid, i + 1)] = __float2bfloat16(0.f);
    }

    // Per-group Qu fragment pointers (group g = rows i0+g*16 .. +15).
    const __hip_bfloat16* qup0 =
        Qu + (tokbase + i0 + c16) * 1024 + headoff + quad * 8;

    // au loaded once and held; a = au + (v-u) derived for phase 2.
    bf16x8 au[4][2];
    #pragma unroll
    for (int g = 0; g < 4; ++g) {
        au[g][0] = ldg8(qup0 + (size_t)g * 16 * 1024);
        au[g][1] = ldg8(qup0 + (size_t)g * 16 * 1024 + 32);
    }

    // K register prefetch: latency overlapped with phase 2's work.
    bf16x8 kf[8][2];
    #pragma unroll
    for (int t = 0; t < 8; ++t) {
        const int c0 = w * 128 + t * 16;
        const __hip_bfloat16* kp =
            Kb + (tokbase + c0 + c16) * 1024 + headoff + quad * 8;
        kf[t][0] = ldg8(kp);
        kf[t][1] = ldg8(kp + 32);
    }

    // Phase 2: BD_raw = (q+v)·r^T for 64 rows, scattered through rel-shift.
    // bd_raw row j, col l -> out row j   at c = l+j-1023  (l >= 1023-j)
    //                     -> out row j-1 at c = l+j+1     (l <= 1022-j)
    {
        bf16x8 a[4][2];
        #pragma unroll
        for (int g = 0; g < 4; ++g)
            #pragma unroll
            for (int j = 0; j < 8; ++j) {
                const int d = quad * 8 + j;
                a[g][0][j] = f2b(b2f(au[g][0][j]) + (vvec[d] - uvec[d]));
                a[g][1][j] = f2b(b2f(au[g][1][j]) + (vvec[d + 32] - uvec[d + 32]));
            }
        for (int t = 0; t < 8; ++t) {
            const int l0 = w * 128 + t * 16;
            const __hip_bfloat16* rp =
                Posb + (tokbase + l0 + c16) * 1024 + headoff + quad * 8;
            const bf16x8 r0 = ldg8(rp);
            const bf16x8 r1 = ldg8(rp + 32);
            const int l = l0 + c16;
            #pragma unroll
            for (int g = 0; g < 4; ++g) {
                f32x4 c = (f32x4){0.f, 0.f, 0.f, 0.f};
                c = MFMA16(a[g][0], r0, c);
                c = MFMA16(a[g][1], r1, c);
                #pragma unroll
                for (int r = 0; r < 4; ++r) {
                    const int jl = g * 16 + quad * 4 + r;  // local bd_raw row
                    const int j  = i0 + jl;
                    const __bf16 val = f2b(c[r]);
                    if (l >= 1023 - j) Ls[lidx16(jl, l + j - 1023)] =
                        __builtin_bit_cast(__hip_bfloat16, val);
                    if (jl >= 1 && l <= 1022 - j) Ls[lidx16(jl - 1, l + j + 1)] =
                        __builtin_bit_cast(__hip_bfloat16, val);
                }
            }
        }
    }

    // Phase 3: extra bd_raw row j2 = i0+64 feeds local row 63 at c >= i0+65.
    if (j2 < 1024) {
        for (int c = i0 + 65 + tid; c < 1024; c += 512) {
            const int l = c - i0 - 65;
            const __hip_bfloat16* rp = Posb + (tokbase + l) * 1024 + headoff;
            float s = 0.f;
            #pragma unroll
            for (int d8 = 0; d8 < 8; ++d8) {
                const bf16x8 rv = ldg8(rp + d8 * 8);
                #pragma unroll
                for (int j = 0; j < 8; ++j)
                    s += q2s[d8 * 8 + j] * b2f(rv[j]);
            }
            Ls[lidx16(63, c)] = __float2bfloat16(s);
        }
    }
    __syncthreads();

    // Phase 4: AC = (q+u)·k^T from prefetched registers; fused
    // P = exp2((bd+ac)*log2e/32 - 4*log2e) (= exp(logit - 4)).
    {
        const float C1 = 1.44269504f * 0.03125f;   // log2(e) * SCALE
        const float C2 = -5.77078016f;             // -4 * log2(e)
        float sums[4][4] = {};
        for (int t = 0; t < 8; ++t) {
            const int cc = w * 128 + t * 16 + c16;
            #pragma unroll
            for (int g = 0; g < 4; ++g) {
                f32x4 c = (f32x4){0.f, 0.f, 0.f, 0.f};
                c = MFMA16(au[g][0], kf[t][0], c);
                c = MFMA16(au[g][1], kf[t][1], c);
                #pragma unroll
                for (int r = 0; r < 4; ++r) {
                    const int il = g * 16 + quad * 4 + r;
                    const int idx = lidx16(il, cc);
                    const float lg = __bfloat162float(Ls[idx]) + c[r];
                    const float p = __builtin_amdgcn_exp2f(fmaf(lg, C1, C2));
                    sums[g][r] += p;
                    Ls[idx] = __float2bfloat16(p);
                }
            }
        }
        #pragma unroll
        for (int g = 0; g < 4; ++g)
            #pragma unroll
            for (int r = 0; r < 4; ++r) {
                float s = sums[g][r];
                s += __shfl_xor(s, 1);
                s += __shfl_xor(s, 2);
                s += __shfl_xor(s, 4);
                s += __shfl_xor(s, 8);
                if (c16 == 0) Wsum[(g * 16 + quad * 4 + r) * 8 + w] = s;
            }
    }
    __syncthreads();

    if (tid < 64) {
        float s = 0.f;
        #pragma unroll
        for (int k = 0; k < 8; ++k) s += Wsum[tid * 8 + k];
        rs[tid] = 1.f / s;
    }
    __syncthreads();

    // Phase 6: O = (P @ V) * rinv for all 4 row groups.
    // Wave w: d-tile d0=(w&3)*16, k-half kh=w>>2; V load shared by groups.
    {
        const int d0 = (w & 3) * 16;
        const int kh = w >> 2;
        const __hip_bfloat16* vp =
            Vt + ((size_t)bh * 64 + d0 + c16) * 1024 + quad * 8;
        f32x4 acc[4] = {};
        for (int kk = kh * 512; kk < kh * 512 + 512; kk += 32) {
            const bf16x8 vld = ldg8(vp + kk);
            #pragma unroll
            for (int g = 0; g < 4; ++g) {
                const bf16x8 p =
                    *(const bf16x8*)&Ls[lidx16(g * 16 + c16, kk + quad * 8)];
                acc[g] = MFMA16(p, vld, acc[g]);
            }
        }
        __syncthreads();   // all P reads done; logits LDS now reusable
        float* Lf = (float*)Ls;
        const int sbase = (w & 3) * 1024;
        if (kh == 1) {
            #pragma unroll
            for (int g = 0; g < 4; ++g)
                #pragma unroll
                for (int r = 0; r < 4; ++r)
                    Lf[sbase + g * 256 + (quad * 4 + r) * 16 + c16] = acc[g][r];
        }
        __syncthreads();
        if (kh == 0) {
            #pragma unroll
            for (int g = 0; g < 4; ++g)
                #pragma unroll
                for (int r = 0; r < 4; ++r) {
                    const int il = g * 16 + quad * 4 + r;
                    const float val =
                        (acc[g][r] + Lf[sbase + g * 256 + (quad * 4 + r) * 16 + c16])
                        * rs[il];
                    const int i = i0 + il;
                    const int d = d0 + c16;
                    O[(tokbase + i) * 1024 + headoff + d] = __float2bfloat16(val);
                }
        }
    }
}

// ---------------------------------------------------------------------------
extern "C" void kernel_launch(void* const* d_in, const int* in_sizes, int n_in,
                              void* d_out, int out_size, void* d_ws, size_t ws_size,
                              hipStream_t stream)
{
    const float* x   = (const float*)d_in[0];
    const float* u   = (const float*)d_in[1];
    const float* v   = (const float*)d_in[2];
    const float* pos = (const float*)d_in[3];
    const float* Wq  = (const float*)d_in[4];
    const float* bq  = (const float*)d_in[5];
    const float* Wk  = (const float*)d_in[6];
    const float* bk  = (const float*)d_in[7];
    const float* Wv  = (const float*)d_in[8];
    const float* bv  = (const float*)d_in[9];
    const float* Wc  = (const float*)d_in[10];
    const float* bc  = (const float*)d_in[11];

    const size_t MB = (size_t)1 << 20;
    char* ws = (char*)d_ws;
    __hip_bfloat16* Qu    = (__hip_bfloat16*)(ws + 0 * MB);
    __hip_bfloat16* Kb    = (__hip_bfloat16*)(ws + 8 * MB);
    __hip_bfloat16* Vt    = (__hip_bfloat16*)(ws + 16 * MB);
    __hip_bfloat16* xb    = (__hip_bfloat16*)(ws + 24 * MB);  // aliased w/ O
    __hip_bfloat16* O     = (__hip_bfloat16*)(ws + 24 * MB);  // x dead after QKV
    __hip_bfloat16* Posb  = (__hip_bfloat16*)(ws + 32 * MB);
    __hip_bfloat16* Wqkvb = (__hip_bfloat16*)(ws + 40 * MB);
    __hip_bfloat16* Wcb   = (__hip_bfloat16*)(ws + 46 * MB);

    cvt_kernel<<<6144, 256, 0, stream>>>(x, pos, Wq, Wk, Wv, Wc,
                                         xb, Posb, Wqkvb, Wcb);

    gemm_qkv<<<dim3(24, 32), dim3(256), 0, stream>>>(
        xb, Wqkvb, bq, bk, bv, u, Qu, Kb, Vt);

    attn_kernel<<<dim3(16, 64), dim3(512), 0, stream>>>(
        Qu, Kb, Posb, Vt, u, v, O);

    gemm_fin<<<dim3(16, 32), dim3(256), 0, stream>>>(
        O, Wcb, (float*)d_out, bc);
}

// Round 15
// 282.717 us; speedup vs baseline: 1.1258x; 1.0552x over previous
//
#include <hip/hip_runtime.h>
#include <hip/hip_bf16.h>

// RelAttention (Transformer-XL style) on MI355X.
// fp32 in/out; internal bf16 MFMA w/ fp32 accum.
// B=4, S=1024, D=1024, H=16, DH=64, BH=64. SCALE = 1/32.
//
// Pipeline: cvt -> fused QKV GEMM (m97-style) -> fused rel-attention
// (64-row tiles, 512 thr, r11 structure; XCD-local grid: bh on blockIdx.x
// so all 16 row-tiles of a head share one XCD's L2) -> final GEMM (64x64).

typedef __bf16 bf16x8 __attribute__((ext_vector_type(8)));
typedef float  f32x4  __attribute__((ext_vector_type(4)));
typedef unsigned short u16x4 __attribute__((ext_vector_type(4)));

struct alignas(16) U128 { unsigned long long lo, hi; };

__device__ __forceinline__ bf16x8 ldg8(const __hip_bfloat16* p) {
    U128 u = *reinterpret_cast<const U128*>(p);
    return __builtin_bit_cast(bf16x8, u);
}

__device__ __forceinline__ __bf16 f2b(float f) {
    __hip_bfloat16 h = __float2bfloat16(f);
    return __builtin_bit_cast(__bf16, h);
}
__device__ __forceinline__ unsigned short f2bu(float f) {
    __hip_bfloat16 h = __float2bfloat16(f);
    return __builtin_bit_cast(unsigned short, h);
}
__device__ __forceinline__ float b2f(__bf16 b) {
    __hip_bfloat16 h = __builtin_bit_cast(__hip_bfloat16, b);
    return __bfloat162float(h);
}

__device__ __forceinline__ bf16x8 ldg8cvt(const float* p) {
    f32x4 a = *reinterpret_cast<const f32x4*>(p);
    f32x4 b = *reinterpret_cast<const f32x4*>(p + 4);
    bf16x8 r;
    r[0] = f2b(a[0]); r[1] = f2b(a[1]); r[2] = f2b(a[2]); r[3] = f2b(a[3]);
    r[4] = f2b(b[0]); r[5] = f2b(b[1]); r[6] = f2b(b[2]); r[7] = f2b(b[3]);
    return r;
}

#define MFMA16(a, b, c) __builtin_amdgcn_mfma_f32_16x16x32_bf16((a), (b), (c), 0, 0, 0)

__device__ __forceinline__ void gll16(const __hip_bfloat16* g, void* lds_wave_base) {
    __builtin_amdgcn_global_load_lds(
        (const __attribute__((address_space(1))) void*)g,
        (__attribute__((address_space(3))) void*)lds_wave_base,
        16, 0, 0);
}

// ---------------------------------------------------------------------------
// fp32 -> bf16: x(4M), pos(4M), Wq/Wk/Wv(3M stacked), Wc(1M) = 12M elems.
// ---------------------------------------------------------------------------
__global__ __launch_bounds__(256) void cvt_kernel(
    const float* __restrict__ x,  const float* __restrict__ pos,
    const float* __restrict__ wq, const float* __restrict__ wk,
    const float* __restrict__ wv, const float* __restrict__ wc,
    __hip_bfloat16* __restrict__ xb, __hip_bfloat16* __restrict__ posb,
    __hip_bfloat16* __restrict__ wqkvb, __hip_bfloat16* __restrict__ wcb)
{
    const size_t base = ((size_t)blockIdx.x * 256 + threadIdx.x) * 8;
    const size_t M1 = (size_t)1 << 20;
    const float* src; __hip_bfloat16* dst; size_t o;
    if (base < 4*M1)        { src = x;   dst = xb;           o = base; }
    else if (base < 8*M1)   { src = pos; dst = posb;         o = base - 4*M1; }
    else if (base < 9*M1)   { src = wq;  dst = wqkvb;        o = base - 8*M1; }
    else if (base < 10*M1)  { src = wk;  dst = wqkvb + M1;   o = base - 9*M1; }
    else if (base < 11*M1)  { src = wv;  dst = wqkvb + 2*M1; o = base - 10*M1; }
    else                    { src = wc;  dst = wcb;          o = base - 11*M1; }
    *(bf16x8*)(dst + o) = ldg8cvt(src + o);
}

// ---------------------------------------------------------------------------
// QKV GEMM (m97-style): C[m][n] = sum_k A[m][k]*Bm[n][k], Bm=[3072][1024].
// n<1024 -> Qu = C+bq+u; <2048 -> Kb = C+bk; else Vt head-transposed = C+bv.
// ---------------------------------------------------------------------------
__global__ __launch_bounds__(256) void gemm_qkv(
    const __hip_bfloat16* __restrict__ A,
    const __hip_bfloat16* __restrict__ Bm,
    const float* __restrict__ bq, const float* __restrict__ bk,
    const float* __restrict__ bv, const float* __restrict__ u,
    __hip_bfloat16* __restrict__ Qu,
    __hip_bfloat16* __restrict__ Kb, __hip_bfloat16* __restrict__ Vt)
{
    __shared__ __hip_bfloat16 As[128 * 32];
    __shared__ __hip_bfloat16 Bs[128 * 32];

    const int tid  = threadIdx.x;
    const int lane = tid & 63, w = tid >> 6;
    const int quad = lane >> 4, c16 = lane & 15;
    const int wm = w >> 1, wn = w & 1;
    const int m0 = blockIdx.y * 128;
    const int n0 = blockIdx.x * 128;

    const int srow = w * 16 + (lane >> 2);
    const int scol = (lane & 3) * 8;
    const __hip_bfloat16* gA0 = A  + (size_t)(m0 + srow) * 1024 + scol;
    const __hip_bfloat16* gA1 = gA0 + (size_t)64 * 1024;
    const __hip_bfloat16* gB0 = Bm + (size_t)(n0 + srow) * 1024 + scol;
    const __hip_bfloat16* gB1 = gB0 + (size_t)64 * 1024;
    char* ldsA0 = (char*)As + (w << 10);
    char* ldsA1 = ldsA0 + 4096;
    char* ldsB0 = (char*)Bs + (w << 10);
    char* ldsB1 = ldsB0 + 4096;

    f32x4 acc[4][4] = {};

    for (int k0 = 0; k0 < 1024; k0 += 32) {
        gll16(gA0 + k0, ldsA0);
        gll16(gA1 + k0, ldsA1);
        gll16(gB0 + k0, ldsB0);
        gll16(gB1 + k0, ldsB1);
        __syncthreads();

        bf16x8 af[4], bfr[4];
        #pragma unroll
        for (int i = 0; i < 4; ++i) {
            af[i]  = *(const bf16x8*)&As[(wm * 64 + i * 16 + c16) * 32 + quad * 8];
            bfr[i] = *(const bf16x8*)&Bs[(wn * 64 + i * 16 + c16) * 32 + quad * 8];
        }
        #pragma unroll
        for (int mi = 0; mi < 4; ++mi)
            #pragma unroll
            for (int ni = 0; ni < 4; ++ni)
                acc[mi][ni] = MFMA16(af[mi], bfr[ni], acc[mi][ni]);
        __syncthreads();
    }

    #pragma unroll
    for (int mi = 0; mi < 4; ++mi) {
        #pragma unroll
        for (int ni = 0; ni < 4; ++ni) {
            const int m = m0 + wm * 64 + mi * 16 + quad * 4;  // +r
            const int n = n0 + wn * 64 + ni * 16 + c16;
            if (n < 1024) {
                const float b0 = bq[n] + u[n & 63];
                #pragma unroll
                for (int r = 0; r < 4; ++r)
                    Qu[(size_t)(m + r) * 1024 + n] =
                        __float2bfloat16(acc[mi][ni][r] + b0);
            } else if (n < 2048) {
                const int nn = n - 1024;
                const float b0 = bk[nn];
                #pragma unroll
                for (int r = 0; r < 4; ++r)
                    Kb[(size_t)(m + r) * 1024 + nn] =
                        __float2bfloat16(acc[mi][ni][r] + b0);
            } else {
                const int nn = n - 2048;
                const float b0 = bv[nn];
                const int d = nn & 63, hh = nn >> 6;
                const int bb = m >> 10, s = m & 1023;
                u16x4 pk;
                #pragma unroll
                for (int r = 0; r < 4; ++r)
                    pk[r] = f2bu(acc[mi][ni][r] + b0);
                *(u16x4*)&Vt[(((size_t)(bb * 16 + hh) * 64 + d) << 10) + s] = pk;
            }
        }
    }
}

// ---------------------------------------------------------------------------
// Final GEMM, 64x64 tiles (grid 16x64 = 1024 blocks -> 4 blocks/CU).
// ---------------------------------------------------------------------------
__global__ __launch_bounds__(256) void gemm_fin64(
    const __hip_bfloat16* __restrict__ A,
    const __hip_bfloat16* __restrict__ Bm,
    float* __restrict__ dout, const float* __restrict__ bc)
{
    __shared__ __hip_bfloat16 As[64 * 32];
    __shared__ __hip_bfloat16 Bs[64 * 32];

    const int tid  = threadIdx.x;
    const int lane = tid & 63, w = tid >> 6;
    const int quad = lane >> 4, c16 = lane & 15;
    const int wm = w >> 1, wn = w & 1;
    const int m0 = blockIdx.y * 64;
    const int n0 = blockIdx.x * 64;

    const int srow = w * 16 + (lane >> 2);
    const int scol = (lane & 3) * 8;
    const __hip_bfloat16* gA = A  + (size_t)(m0 + srow) * 1024 + scol;
    const __hip_bfloat16* gB = Bm + (size_t)(n0 + srow) * 1024 + scol;
    char* ldsA = (char*)As + (w << 10);
    char* ldsB = (char*)Bs + (w << 10);

    f32x4 acc[2][2] = {};

    for (int k0 = 0; k0 < 1024; k0 += 32) {
        gll16(gA + k0, ldsA);
        gll16(gB + k0, ldsB);
        __syncthreads();

        bf16x8 af[2], bfr[2];
        #pragma unroll
        for (int i = 0; i < 2; ++i) {
            af[i]  = *(const bf16x8*)&As[(wm * 32 + i * 16 + c16) * 32 + quad * 8];
            bfr[i] = *(const bf16x8*)&Bs[(wn * 32 + i * 16 + c16) * 32 + quad * 8];
        }
        #pragma unroll
        for (int mi = 0; mi < 2; ++mi)
            #pragma unroll
            for (int ni = 0; ni < 2; ++ni)
                acc[mi][ni] = MFMA16(af[mi], bfr[ni], acc[mi][ni]);
        __syncthreads();
    }

    #pragma unroll
    for (int mi = 0; mi < 2; ++mi) {
        #pragma unroll
        for (int ni = 0; ni < 2; ++ni) {
            const int m = m0 + wm * 32 + mi * 16 + quad * 4;
            const int n = n0 + wn * 32 + ni * 16 + c16;
            const float b0 = bc[n];
            #pragma unroll
            for (int r = 0; r < 4; ++r)
                dout[(size_t)(m + r) * 1024 + n] = acc[mi][ni][r] + b0;
        }
    }
}

// ---------------------------------------------------------------------------
// Fused relative attention, 64-row tiles, 512 threads (8 waves) — r11
// structure. Grid is (bh, i0-tile) so the 16 tiles of one head have linear
// block ids congruent mod 8 -> same XCD -> K/Pos/V head slices stay hot in
// that XCD's 4 MiB L2 (1 block/CU: ~8 heads x 384 KB = 3 MB resident).
// Logits in LDS as bf16 [64][1024] = 128 KiB; XOR swizzle at 16B granularity.
// Fixed-shift softmax fused into AC pass; deferred normalization after PV.
// ---------------------------------------------------------------------------
__device__ __forceinline__ int lidx16(int row, int c) {
    return (row << 10) + ((((c >> 3) ^ row) << 3) | (c & 7));
}

__global__ __launch_bounds__(512) void attn_kernel(
    const __hip_bfloat16* __restrict__ Qu,   // [4096][1024] (q+bq+u)
    const __hip_bfloat16* __restrict__ Kb,   // [4096][1024]
    const __hip_bfloat16* __restrict__ Posb, // [4096][1024] bf16 pos
    const __hip_bfloat16* __restrict__ Vt,   // [bh*64+d][s]
    const float* __restrict__ uvec, const float* __restrict__ vvec,
    __hip_bfloat16* __restrict__ O)          // [4096][1024]
{
    __shared__ __hip_bfloat16 Ls[64 * 1024];   // 128 KiB
    __shared__ float q2s[64];
    __shared__ float Wsum[64 * 8];             // per-(row, wave) partial sums
    __shared__ float rs[64];                   // per-row 1/sum

    const int tid  = threadIdx.x;
    const int lane = tid & 63, w = tid >> 6;   // w in [0,8)
    const int quad = lane >> 4, c16 = lane & 15;
    const int i0 = blockIdx.y * 64;            // row tile
    const int bh = blockIdx.x;                 // head (XCD-local: id % 8 = bh % 8)
    const int b = bh >> 4, h = bh & 15;
    const size_t headoff = (size_t)h * 64;
    const size_t tokbase = (size_t)b * 1024;
    const int j2 = i0 + 64;

    // q2s = (q+v) row j2 (fp32), for phase 3.
    if (tid < 64) {
        float val = 0.f;
        if (j2 < 1024)
            val = b2f(__builtin_bit_cast(__bf16,
                      Qu[(tokbase + j2) * 1024 + headoff + tid])) +
                  (vvec[tid] - uvec[tid]);
        q2s[tid] = val;
    }
    __syncthreads();

    // Phase 1: the rel-shift leaves exactly one zero per row, at c = i+1.
    if (tid < 64) {
        const int i = i0 + tid;
        if (i + 1 < 1024) Ls[lidx16(tid, i + 1)] = __float2bfloat16(0.f);
    }

    // Per-group Qu fragment pointers (group g = rows i0+g*16 .. +15).
    const __hip_bfloat16* qup0 =
        Qu + (tokbase + i0 + c16) * 1024 + headoff + quad * 8;

    // Phase 2: BD_raw = (q+v)·r^T for 64 rows, scattered through rel-shift.
    // bd_raw row j, col l -> out row j   at c = l+j-1023  (l >= 1023-j)
    //                     -> out row j-1 at c = l+j+1     (l <= 1022-j)
    {
        bf16x8 a[4][2];
        #pragma unroll
        for (int g = 0; g < 4; ++g) {
            a[g][0] = ldg8(qup0 + (size_t)g * 16 * 1024);
            a[g][1] = ldg8(qup0 + (size_t)g * 16 * 1024 + 32);
            #pragma unroll
            for (int j = 0; j < 8; ++j) {
                const int d = quad * 8 + j;
                a[g][0][j] = f2b(b2f(a[g][0][j]) + (vvec[d] - uvec[d]));
                a[g][1][j] = f2b(b2f(a[g][1][j]) + (vvec[d + 32] - uvec[d + 32]));
            }
        }
        for (int t = 0; t < 8; ++t) {
            const int l0 = w * 128 + t * 16;
            const __hip_bfloat16* rp =
                Posb + (tokbase + l0 + c16) * 1024 + headoff + quad * 8;
            const bf16x8 r0 = ldg8(rp);
            const bf16x8 r1 = ldg8(rp + 32);
            const int l = l0 + c16;
            #pragma unroll
            for (int g = 0; g < 4; ++g) {
                f32x4 c = (f32x4){0.f, 0.f, 0.f, 0.f};
                c = MFMA16(a[g][0], r0, c);
                c = MFMA16(a[g][1], r1, c);
                #pragma unroll
                for (int r = 0; r < 4; ++r) {
                    const int jl = g * 16 + quad * 4 + r;  // local bd_raw row
                    const int j  = i0 + jl;
                    const __bf16 val = f2b(c[r]);
                    if (l >= 1023 - j) Ls[lidx16(jl, l + j - 1023)] =
                        __builtin_bit_cast(__hip_bfloat16, val);
                    if (jl >= 1 && l <= 1022 - j) Ls[lidx16(jl - 1, l + j + 1)] =
                        __builtin_bit_cast(__hip_bfloat16, val);
                }
            }
        }
    }

    // Phase 3: extra bd_raw row j2 = i0+64 feeds local row 63 at c >= i0+65.
    if (j2 < 1024) {
        for (int c = i0 + 65 + tid; c < 1024; c += 512) {
            const int l = c - i0 - 65;
            const __hip_bfloat16* rp = Posb + (tokbase + l) * 1024 + headoff;
            float s = 0.f;
            #pragma unroll
            for (int d8 = 0; d8 < 8; ++d8) {
                const bf16x8 rv = ldg8(rp + d8 * 8);
                #pragma unroll
                for (int j = 0; j < 8; ++j)
                    s += q2s[d8 * 8 + j] * b2f(rv[j]);
            }
            Ls[lidx16(63, c)] = __float2bfloat16(s);
        }
    }
    __syncthreads();

    // Phase 4: AC = (q+u)·k^T; fused P = exp2((bd+ac)*log2e/32 - 4*log2e)
    // (= exp(logit - 4); softmax shift-invariance + bounded logits).
    {
        bf16x8 au[4][2];
        #pragma unroll
        for (int g = 0; g < 4; ++g) {
            au[g][0] = ldg8(qup0 + (size_t)g * 16 * 1024);
            au[g][1] = ldg8(qup0 + (size_t)g * 16 * 1024 + 32);
        }
        const float C1 = 1.44269504f * 0.03125f;   // log2(e) * SCALE
        const float C2 = -5.77078016f;             // -4 * log2(e)
        float sums[4][4] = {};
        for (int t = 0; t < 8; ++t) {
            const int c0 = w * 128 + t * 16;
            const __hip_bfloat16* kp =
                Kb + (tokbase + c0 + c16) * 1024 + headoff + quad * 8;
            const bf16x8 k0 = ldg8(kp);
            const bf16x8 k1 = ldg8(kp + 32);
            const int cc = c0 + c16;
            #pragma unroll
            for (int g = 0; g < 4; ++g) {
                f32x4 c = (f32x4){0.f, 0.f, 0.f, 0.f};
                c = MFMA16(au[g][0], k0, c);
                c = MFMA16(au[g][1], k1, c);
                #pragma unroll
                for (int r = 0; r < 4; ++r) {
                    const int il = g * 16 + quad * 4 + r;
                    const int idx = lidx16(il, cc);
                    const float lg = __bfloat162float(Ls[idx]) + c[r];
                    const float p = __builtin_amdgcn_exp2f(fmaf(lg, C1, C2));
                    sums[g][r] += p;
                    Ls[idx] = __float2bfloat16(p);
                }
            }
        }
        #pragma unroll
        for (int g = 0; g < 4; ++g)
            #pragma unroll
            for (int r = 0; r < 4; ++r) {
                float s = sums[g][r];
                s += __shfl_xor(s, 1);
                s += __shfl_xor(s, 2);
                s += __shfl_xor(s, 4);
                s += __shfl_xor(s, 8);
                if (c16 == 0) Wsum[(g * 16 + quad * 4 + r) * 8 + w] = s;
            }
    }
    __syncthreads();

    if (tid < 64) {
        float s = 0.f;
        #pragma unroll
        for (int k = 0; k < 8; ++k) s += Wsum[tid * 8 + k];
        rs[tid] = 1.f / s;
    }
    __syncthreads();

    // Phase 6: O = (P @ V) * rinv for all 4 row groups.
    // Wave w: d-tile d0=(w&3)*16, k-half kh=w>>2; V load shared by groups.
    {
        const int d0 = (w & 3) * 16;
        const int kh = w >> 2;
        const __hip_bfloat16* vp =
            Vt + ((size_t)bh * 64 + d0 + c16) * 1024 + quad * 8;
        f32x4 acc[4] = {};
        for (int kk = kh * 512; kk < kh * 512 + 512; kk += 32) {
            const bf16x8 vld = ldg8(vp + kk);
            #pragma unroll
            for (int g = 0; g < 4; ++g) {
                const bf16x8 p =
                    *(const bf16x8*)&Ls[lidx16(g * 16 + c16, kk + quad * 8)];
                acc[g] = MFMA16(p, vld, acc[g]);
            }
        }
        __syncthreads();   // all P reads done; logits LDS now reusable
        float* Lf = (float*)Ls;
        const int sbase = (w & 3) * 1024;
        if (kh == 1) {
            #pragma unroll
            for (int g = 0; g < 4; ++g)
                #pragma unroll
                for (int r = 0; r < 4; ++r)
                    Lf[sbase + g * 256 + (quad * 4 + r) * 16 + c16] = acc[g][r];
        }
        __syncthreads();
        if (kh == 0) {
            #pragma unroll
            for (int g = 0; g < 4; ++g)
                #pragma unroll
                for (int r = 0; r < 4; ++r) {
                    const int il = g * 16 + quad * 4 + r;
                    const float val =
                        (acc[g][r] + Lf[sbase + g * 256 + (quad * 4 + r) * 16 + c16])
                        * rs[il];
                    const int i = i0 + il;
                    const int d = d0 + c16;
                    O[(tokbase + i) * 1024 + headoff + d] = __float2bfloat16(val);
                }
        }
    }
}

// ---------------------------------------------------------------------------
extern "C" void kernel_launch(void* const* d_in, const int* in_sizes, int n_in,
                              void* d_out, int out_size, void* d_ws, size_t ws_size,
                              hipStream_t stream)
{
    const float* x   = (const float*)d_in[0];
    const float* u   = (const float*)d_in[1];
    const float* v   = (const float*)d_in[2];
    const float* pos = (const float*)d_in[3];
    const float* Wq  = (const float*)d_in[4];
    const float* bq  = (const float*)d_in[5];
    const float* Wk  = (const float*)d_in[6];
    const float* bk  = (const float*)d_in[7];
    const float* Wv  = (const float*)d_in[8];
    const float* bv  = (const float*)d_in[9];
    const float* Wc  = (const float*)d_in[10];
    const float* bc  = (const float*)d_in[11];

    const size_t MB = (size_t)1 << 20;
    char* ws = (char*)d_ws;
    __hip_bfloat16* Qu    = (__hip_bfloat16*)(ws + 0 * MB);
    __hip_bfloat16* Kb    = (__hip_bfloat16*)(ws + 8 * MB);
    __hip_bfloat16* Vt    = (__hip_bfloat16*)(ws + 16 * MB);
    __hip_bfloat16* xb    = (__hip_bfloat16*)(ws + 24 * MB);  // aliased w/ O
    __hip_bfloat16* O     = (__hip_bfloat16*)(ws + 24 * MB);  // x dead after QKV
    __hip_bfloat16* Posb  = (__hip_bfloat16*)(ws + 32 * MB);
    __hip_bfloat16* Wqkvb = (__hip_bfloat16*)(ws + 40 * MB);
    __hip_bfloat16* Wcb   = (__hip_bfloat16*)(ws + 46 * MB);

    cvt_kernel<<<6144, 256, 0, stream>>>(x, pos, Wq, Wk, Wv, Wc,
                                         xb, Posb, Wqkvb, Wcb);

    gemm_qkv<<<dim3(24, 32), dim3(256), 0, stream>>>(
        xb, Wqkvb, bq, bk, bv, u, Qu, Kb, Vt);

    attn_kernel<<<dim3(64, 16), dim3(512), 0, stream>>>(
        Qu, Kb, Posb, Vt, u, v, O);

    gemm_fin64<<<dim3(16, 64), dim3(256), 0, stream>>>(
        O, Wcb, (float*)d_out, bc);
}